// Round 11
// baseline (120.573 us; speedup 1.0000x reference)
//
#include <hip/hip_runtime.h>
#include <stdint.h>

#pragma clang fp contract(off)

#define BATCH 8
#define NANCH 200000
#define NGT   20
#define APT   3             // R10: 9->3 — kill VGPR spills; fill 8 waves/SIMD
#define CHUNK (256*APT)     // 768
#define PB    261           // chunks per batch; 261*768 = 200448 >= 200000
#define GRID  (PB*BATCH)    // 2088 blocks ≈ 8 blocks/CU resident at 64 VGPR
#define HBINS 1024          // fg: coarse bins (rb14>>4); bg: fine bins rb14<1024
#define HWORDS (2*BATCH*HBINS)  // 16384 words = 64 KB total
#define NWAVES (GRID*4)     // 8352 waves
#define HALF_FLAT 800000u   // (BATCH*NANCH)/2 threefry split

// ---- compile-time threefry for the two split keys ----
constexpr void ctf_round(uint32_t& x0, uint32_t& x1, int r) {
  x0 += x1; x1 = (x1 << r) | (x1 >> (32 - r)); x1 ^= x0;
}
constexpr uint64_t cenc(uint32_t k0, uint32_t k1, uint32_t x0, uint32_t x1) {
  uint32_t k2 = k0 ^ k1 ^ 0x1BD11BDAu;
  x0 += k0; x1 += k1;
  ctf_round(x0,x1,13); ctf_round(x0,x1,15); ctf_round(x0,x1,26); ctf_round(x0,x1,6);
  x0 += k1; x1 += k2 + 1u;
  ctf_round(x0,x1,17); ctf_round(x0,x1,29); ctf_round(x0,x1,16); ctf_round(x0,x1,24);
  x0 += k2; x1 += k0 + 2u;
  ctf_round(x0,x1,13); ctf_round(x0,x1,15); ctf_round(x0,x1,26); ctf_round(x0,x1,6);
  x0 += k0; x1 += k1 + 3u;
  ctf_round(x0,x1,17); ctf_round(x0,x1,29); ctf_round(x0,x1,16); ctf_round(x0,x1,24);
  x0 += k1; x1 += k2 + 4u;
  ctf_round(x0,x1,13); ctf_round(x0,x1,15); ctf_round(x0,x1,26); ctf_round(x0,x1,6);
  x0 += k2; x1 += k0 + 5u;
  return ((uint64_t)x1 << 32) | x0;
}
constexpr uint64_t EA = cenc(0u,42u,0u,2u);
constexpr uint64_t EB = cenc(0u,42u,1u,3u);
#define KF0 ((uint32_t)(EA & 0xFFFFFFFFu))
#define KF1 ((uint32_t)(EB & 0xFFFFFFFFu))
#define KG0 ((uint32_t)(EA >> 32))
#define KG1 ((uint32_t)(EB >> 32))

// ---- runtime threefry ----
__device__ __forceinline__ void tf_round(uint32_t& x0, uint32_t& x1, int r) {
  x0 += x1; x1 = (x1 << r) | (x1 >> (32 - r)); x1 ^= x0;
}
__device__ __forceinline__ void threefry2x32(uint32_t k0, uint32_t k1,
                                             uint32_t x0, uint32_t x1,
                                             uint32_t& o0, uint32_t& o1) {
  uint32_t k2 = k0 ^ k1 ^ 0x1BD11BDAu;
  x0 += k0; x1 += k1;
  tf_round(x0,x1,13); tf_round(x0,x1,15); tf_round(x0,x1,26); tf_round(x0,x1,6);
  x0 += k1; x1 += k2 + 1u;
  tf_round(x0,x1,17); tf_round(x0,x1,29); tf_round(x0,x1,16); tf_round(x0,x1,24);
  x0 += k2; x1 += k0 + 2u;
  tf_round(x0,x1,13); tf_round(x0,x1,15); tf_round(x0,x1,26); tf_round(x0,x1,6);
  x0 += k0; x1 += k1 + 3u;
  tf_round(x0,x1,17); tf_round(x0,x1,29); tf_round(x0,x1,16); tf_round(x0,x1,24);
  x0 += k1; x1 += k2 + 4u;
  tf_round(x0,x1,13); tf_round(x0,x1,15); tf_round(x0,x1,26); tf_round(x0,x1,6);
  x0 += k2; x1 += k0 + 5u;
  o0 = x0; o1 = x1;
}
__device__ __forceinline__ uint32_t rbits23(uint32_t kk0, uint32_t kk1, uint32_t f) {
  uint32_t o0, o1;
  if (f < HALF_FLAT) { threefry2x32(kk0, kk1, f, f + HALF_FLAT, o0, o1); return o0 >> 9; }
  else               { threefry2x32(kk0, kk1, f - HALF_FLAT, f, o0, o1); return o1 >> 9; }
}

// ---- DPP wave64 max-reduce (6 VALU-rate ops, no DS) ----
template<int CTRL>
__device__ __forceinline__ float dppmax(float x) {
  int xi = __float_as_int(x);
  int yi = __builtin_amdgcn_update_dpp(xi, xi, CTRL, 0xf, 0xf, false);
  return fmaxf(x, __int_as_float(yi));
}
__device__ __forceinline__ float wave_max64(float x) {
  x = dppmax<0x0B1>(x);  // quad_perm [1,0,3,2]
  x = dppmax<0x04E>(x);  // quad_perm [2,3,0,1]
  x = dppmax<0x141>(x);  // row_half_mirror
  x = dppmax<0x140>(x);  // row_mirror
  x = dppmax<0x142>(x);  // row_bcast15
  x = dppmax<0x143>(x);  // row_bcast31
  return __int_as_float(__builtin_amdgcn_readlane(__float_as_int(x), 63));
}

// ---- K1: IoU pass + approx hist (R8 verified logic; APT=3, no spills) ----
__global__ __launch_bounds__(256, 8)
void k_main(const float* __restrict__ gt, const float* __restrict__ anc,
            float* __restrict__ wavemax, uint32_t* __restrict__ aux,
            uint16_t* __restrict__ combo, float* __restrict__ out_matches,
            float* __restrict__ out_inds, float* __restrict__ out_anch,
            uint32_t* __restrict__ hist, int* __restrict__ gtmax_bits) {
  const int bid = blockIdx.x, t = threadIdx.x;
  const int b = bid / PB, blk = bid % PB;

  __shared__ float sx1[NGT], sy1[NGT], sx2p[NGT], sy2p[NGT], sar[NGT];
  __shared__ int   ssz[NGT];
  __shared__ int   smax[NGT];
  if (t < NGT) {
    const float* p = gt + (size_t)(b*NGT + t)*5;
    float x1=p[0], y1=p[1], x2=p[2], y2=p[3];
    float w = x2 - x1 + 1.0f, h = y2 - y1 + 1.0f;
    sx1[t]=x1; sy1[t]=y1; sx2p[t]=x2+1.0f; sy2p[t]=y2+1.0f; sar[t]=w*h;
    ssz[t] = (w==1.0f) && (h==1.0f);
    smax[t] = 0xBF800000;   // bits of -1.0f; all real wavemax >= 0.0f
  }
  __syncthreads();

  const float4* a4 = (const float4*)anc;
  const int base = blk*CHUNK + t;
  const int lane = t & 63;
  float4 av[APT]; float aarea[APT], ax2p[APT], ay2p[APT];
  bool anz[APT], valid[APT];
#pragma unroll
  for (int j=0;j<APT;j++) {
    int n = base + j*256;
    valid[j] = n < NANCH;
    if (n > NANCH-1) n = NANCH-1;   // clamped dup: max-neutral, outputs skipped
    av[j] = a4[n];
    float aw = av[j].z-av[j].x+1.0f, ah = av[j].w-av[j].y+1.0f;
    aarea[j] = aw*ah;
    anz[j] = (aw==1.0f)&&(ah==1.0f);
    ax2p[j] = av[j].z + 1.0f;
    ay2p[j] = av[j].w + 1.0f;
  }
  float best[APT]; int arg[APT]; uint32_t Mloc[APT];
#pragma unroll
  for (int j=0;j<APT;j++) { best[j]=-3.0f; arg[j]=0; Mloc[j]=0u; }
  uint32_t kmask = 0u; float wm = 0.0f;
  // ---- hot loop: rolled over k; DPP wave-max fused per-k ----
  for (int k=0;k<NGT;k++) {
    float kx1=sx1[k], ky1=sy1[k], kx2p=sx2p[k], ky2p=sy2p[k], kar=sar[k];
    bool kz = ssz[k];
    float ovv[APT]; float tmk = -3.0f;
#pragma unroll
    for (int j=0;j<APT;j++) {
      float iw = fminf(ax2p[j], kx2p) - fmaxf(av[j].x, kx1);
      float ih = fminf(ay2p[j], ky2p) - fmaxf(av[j].y, ky1);
      float inter = fmaxf(iw,0.0f)*fmaxf(ih,0.0f);
      float ov = inter * __builtin_amdgcn_rcpf((aarea[j] + kar) - inter);
      if (kz)     ov = 0.0f;
      if (anz[j]) ov = -1.0f;
      ovv[j] = ov;
      if (ov > best[j]) { best[j] = ov; arg[j] = k; }  // first-occurrence argmax
      tmk = fmaxf(tmk, ov);
    }
#pragma unroll
    for (int j=0;j<APT;j++) if (ovv[j] == tmk) Mloc[j] |= (1u<<k);
    const float sv = wave_max64(tmk);
    if (tmk == sv)  kmask |= (1u<<k);
    if (lane == k)  wm = sv;
  }
  // ---- post-loop: store wave max, block/global gt_max reduce ----
  const int wid = bid*4 + (t>>6);
  if (lane < NGT) {
    wavemax[(size_t)wid*NGT + lane] = wm;             // one 80B wave store
    atomicMax(&smax[lane], __float_as_int(wm));       // block-level reduce
  }
  __syncthreads();
  if (t < NGT) atomicMax(&gtmax_bits[b*NGT + t], smax[t]);  // 20 atomics/block
  // ---- outputs + approx hist (code' = flags only; promotions fixed later) ----
  float4* oa4 = (float4*)out_anch;
  const bool owner = (b == (blk & 7));   // spread inds/anch writes over batches
#pragma unroll
  for (int j=0;j<APT;j++) {
    int n = base + j*256;
    if (!valid[j]) continue;
    uint32_t a = ((Mloc[j] & kmask)<<2) |
                 ((best[j] >= 0.7f) ? 2u : 0u) | ((best[j] < 0.3f) ? 1u : 0u);
    aux[(size_t)b*NANCH + n] = a;
    out_matches[(size_t)b*NANCH + n] = (float)(arg[j] + b*NGT);
    if (owner) { out_inds[n] = (float)n; oa4[n] = av[j]; }
    if (a & 3u) {                         // code' != 0: hash + hist + combo
      uint32_t f = (uint32_t)(b*NANCH + n);
      bool isfg = (a & 2u) != 0u;
      uint32_t rb14 = rbits23(isfg?KF0:KG0, isfg?KF1:KG1, f) >> 9;
      combo[(size_t)b*NANCH + n] = (uint16_t)rb14;
      if (isfg)                           // fg: sparse, full-range coarse bins
        atomicAdd(&hist[b*2*HBINS + (rb14>>4)], 1u);
      else if (rb14 < HBINS)              // bg: fine bins, cutoff region only
        atomicAdd(&hist[b*2*HBINS + HBINS + rb14], 1u);
    }
  }
}

// ---- K2: resolve true codes, thresholds from approx hist, labels ----
__global__ __launch_bounds__(256, 8)
void k_final(const uint32_t* __restrict__ aux, const uint16_t* __restrict__ combo,
             const float* __restrict__ wavemax, const int* __restrict__ gtmax_bits,
             const uint32_t* __restrict__ hist, float* __restrict__ out_labels) {
  const int bid = blockIdx.x, t = threadIdx.x;
  const int b = bid / PB, blk = bid % PB;
  const int lane = t & 63;
  const int wid = bid*4 + (t>>6);
  __shared__ uint32_t ls[256];
  __shared__ uint32_t s_keptfg;
  __shared__ uint32_t s_thr[2];

  // ---- wk: does this wave achieve the global gt_max for gt k? ----
  bool cond = false;
  if (lane < NGT) {
    float gv = __int_as_float(gtmax_bits[b*NGT + lane]);
    float rep = (gv == 0.0f) ? 1e-5f : gv;            // ref's gt_max fixup
    cond = (wavemax[(size_t)wid*NGT + lane] == rep);
  }
  uint32_t wk = (uint32_t)__ballot(cond);

  // ---- per-batch selection scan (fg coarse, bg fine-with-fallback) ----
  for (int m = 0; m < 2; m++) {
    const uint32_t* h = hist + b*2*HBINS + m*HBINS;   // 4 bins/thread
    const uint4 hv = ((const uint4*)h)[t];            // 16B coalesced load
    uint32_t s = hv.x + hv.y + hv.z + hv.w;
    ls[t] = s; __syncthreads();
#pragma unroll
    for (int off=1; off<256; off<<=1) {
      uint32_t v = (t>=off) ? ls[t-off] : 0u; __syncthreads();
      ls[t] += v; __syncthreads();
    }
    uint32_t total = ls[255];   // m=1: total within cutoff region only
    uint32_t incl  = ls[t], excl = incl - s;
    uint32_t target = (m==0) ? 128u : (256u - s_keptfg);
    if (total <= target) {
      if (t == 0) s_thr[m] = (m==0) ? (HBINS-1u) : 0x3FFFu;  // keep all
    } else if (excl < target && target <= incl) {     // unique owner thread
      uint32_t cum = excl, jj = 4*t;
      if      (cum + hv.x >= target) jj = 4*t;
      else if (cum + hv.x + hv.y >= target) jj = 4*t+1;
      else if (cum + hv.x + hv.y + hv.z >= target) jj = 4*t+2;
      else jj = 4*t+3;
      s_thr[m] = jj;            // fg: coarse units; bg: fine units
    }
    if (m == 0 && t == 0) s_keptfg = (total < 128u) ? total : 128u;
    __syncthreads();
  }
  const uint32_t rF = s_thr[0], rB = s_thr[1];

  // ---- labels: true code; rb from combo (recompute only for promotions) ----
  const int base = blk*CHUNK + t;
#pragma unroll
  for (int j=0;j<APT;j++) {
    int n = base + j*256; if (n >= NANCH) break;
    uint32_t a = aux[(size_t)b*NANCH + n];
    uint32_t rb14 = combo[(size_t)b*NANCH + n];
    uint32_t code = (a & 1u) ? 1u : 0u;
    if ((a>>2) & wk) code = 2u;                       // keep (achieves gt_max)
    if (a & 2u) code = 2u;                            // best >= 0.7
    float o = -1.0f;
    if (code == 1u) {
      o = (rb14 <= rB) ? 0.0f : -1.0f;                // fine compare
    } else if (code == 2u) {
      if (!(a & 2u))                                  // promoted: fg-key rehash
        rb14 = rbits23(KF0, KF1, (uint32_t)(b*NANCH + n)) >> 9;
      o = ((rb14>>4) <= rF) ? 1.0f : -1.0f;           // coarse compare
    }
    out_labels[(size_t)b*NANCH + n] = o;
  }
}

extern "C" void kernel_launch(void* const* d_in, const int* in_sizes, int n_in,
                              void* d_out, int out_size, void* d_ws, size_t ws_size,
                              hipStream_t stream) {
  const float* gt  = (const float*)d_in[1];   // gt_boxes (8,20,5) f32
  const float* anc = (const float*)d_in[4];   // anchors (1,200000,4) f32

  float* out         = (float*)d_out;
  float* out_labels  = out;                                  // [0, 1.6M)
  float* out_matches = out + (size_t)BATCH*NANCH;            // [1.6M, 3.2M)
  float* out_inds    = out + (size_t)2*BATCH*NANCH;          // [3.2M, 3.4M)
  float* out_anch    = out_inds + NANCH;                     // [3.4M, 4.2M)

  char* ws = (char*)d_ws;
  int*      gtmax   = (int*)(ws + 0);             // 160 words; 0xAA poison is a
                                                  // valid atomicMax identity
  uint32_t* hist    = (uint32_t*)(ws + 1024);     // 64 KB (memset node below)
  float*    wavemax = (float*)(ws + 66560);       // 8352 waves * 20 * 4 = 668,160
  uint32_t* aux     = (uint32_t*)(ws + 735232);   // 6.4 MB
  uint16_t* combo   = (uint16_t*)(ws + 7135232);  // 3.2 MB

  // zero hist before k_main's atomics (graph-capture-safe stream memset)
  (void)hipMemsetAsync(hist, 0, HWORDS*sizeof(uint32_t), stream);

  k_main <<<GRID, 256, 0, stream>>>(gt, anc, wavemax, aux, combo, out_matches,
                                    out_inds, out_anch, hist, gtmax);
  k_final<<<GRID, 256, 0, stream>>>(aux, combo, wavemax, gtmax, hist, out_labels);
}

// Round 12
// 115.105 us; speedup vs baseline: 1.0475x; 1.0475x over previous
//
#include <hip/hip_runtime.h>
#include <stdint.h>

#pragma clang fp contract(off)

#define BATCH 8
#define NANCH 200000
#define NGT   20
#define APT   9             // R11 post-mortem: APT=3 regressed; 9 is the optimum
#define CHUNK (256*APT)     // 2304
#define PB    96            // chunks per batch; 96*2304 = 221184 >= 200000
#define GRID  (PB*BATCH)    // 768 = exactly 3 blocks/CU on 256 CUs
#define HBINS 1024          // fg: coarse bins (rb14>>4); bg: fine bins rb14<1024
#define HWORDS (2*BATCH*HBINS)  // 16384 words = 64 KB total
#define HALF_FLAT 800000u   // (BATCH*NANCH)/2 threefry split

// ---- compile-time threefry for the two split keys ----
constexpr void ctf_round(uint32_t& x0, uint32_t& x1, int r) {
  x0 += x1; x1 = (x1 << r) | (x1 >> (32 - r)); x1 ^= x0;
}
constexpr uint64_t cenc(uint32_t k0, uint32_t k1, uint32_t x0, uint32_t x1) {
  uint32_t k2 = k0 ^ k1 ^ 0x1BD11BDAu;
  x0 += k0; x1 += k1;
  ctf_round(x0,x1,13); ctf_round(x0,x1,15); ctf_round(x0,x1,26); ctf_round(x0,x1,6);
  x0 += k1; x1 += k2 + 1u;
  ctf_round(x0,x1,17); ctf_round(x0,x1,29); ctf_round(x0,x1,16); ctf_round(x0,x1,24);
  x0 += k2; x1 += k0 + 2u;
  ctf_round(x0,x1,13); ctf_round(x0,x1,15); ctf_round(x0,x1,26); ctf_round(x0,x1,6);
  x0 += k0; x1 += k1 + 3u;
  ctf_round(x0,x1,17); ctf_round(x0,x1,29); ctf_round(x0,x1,16); ctf_round(x0,x1,24);
  x0 += k1; x1 += k2 + 4u;
  ctf_round(x0,x1,13); ctf_round(x0,x1,15); ctf_round(x0,x1,26); ctf_round(x0,x1,6);
  x0 += k2; x1 += k0 + 5u;
  return ((uint64_t)x1 << 32) | x0;
}
constexpr uint64_t EA = cenc(0u,42u,0u,2u);
constexpr uint64_t EB = cenc(0u,42u,1u,3u);
#define KF0 ((uint32_t)(EA & 0xFFFFFFFFu))
#define KF1 ((uint32_t)(EB & 0xFFFFFFFFu))
#define KG0 ((uint32_t)(EA >> 32))
#define KG1 ((uint32_t)(EB >> 32))

// ---- runtime threefry ----
__device__ __forceinline__ void tf_round(uint32_t& x0, uint32_t& x1, int r) {
  x0 += x1; x1 = (x1 << r) | (x1 >> (32 - r)); x1 ^= x0;
}
__device__ __forceinline__ void threefry2x32(uint32_t k0, uint32_t k1,
                                             uint32_t x0, uint32_t x1,
                                             uint32_t& o0, uint32_t& o1) {
  uint32_t k2 = k0 ^ k1 ^ 0x1BD11BDAu;
  x0 += k0; x1 += k1;
  tf_round(x0,x1,13); tf_round(x0,x1,15); tf_round(x0,x1,26); tf_round(x0,x1,6);
  x0 += k1; x1 += k2 + 1u;
  tf_round(x0,x1,17); tf_round(x0,x1,29); tf_round(x0,x1,16); tf_round(x0,x1,24);
  x0 += k2; x1 += k0 + 2u;
  tf_round(x0,x1,13); tf_round(x0,x1,15); tf_round(x0,x1,26); tf_round(x0,x1,6);
  x0 += k0; x1 += k1 + 3u;
  tf_round(x0,x1,17); tf_round(x0,x1,29); tf_round(x0,x1,16); tf_round(x0,x1,24);
  x0 += k1; x1 += k2 + 4u;
  tf_round(x0,x1,13); tf_round(x0,x1,15); tf_round(x0,x1,26); tf_round(x0,x1,6);
  x0 += k2; x1 += k0 + 5u;
  o0 = x0; o1 = x1;
}
__device__ __forceinline__ uint32_t rbits23(uint32_t kk0, uint32_t kk1, uint32_t f) {
  uint32_t o0, o1;
  if (f < HALF_FLAT) { threefry2x32(kk0, kk1, f, f + HALF_FLAT, o0, o1); return o0 >> 9; }
  else               { threefry2x32(kk0, kk1, f - HALF_FLAT, f, o0, o1); return o1 >> 9; }
}

// ---- DPP wave64 max-reduce (6 VALU-rate ops, no DS) ----
template<int CTRL>
__device__ __forceinline__ float dppmax(float x) {
  int xi = __float_as_int(x);
  int yi = __builtin_amdgcn_update_dpp(xi, xi, CTRL, 0xf, 0xf, false);
  return fmaxf(x, __int_as_float(yi));
}
__device__ __forceinline__ float wave_max64(float x) {
  x = dppmax<0x0B1>(x);  // quad_perm [1,0,3,2]
  x = dppmax<0x04E>(x);  // quad_perm [2,3,0,1]
  x = dppmax<0x141>(x);  // row_half_mirror
  x = dppmax<0x140>(x);  // row_mirror
  x = dppmax<0x142>(x);  // row_bcast15
  x = dppmax<0x143>(x);  // row_bcast31
  return __int_as_float(__builtin_amdgcn_readlane(__float_as_int(x), 63));
}

// ---- K1: IoU pass + approx hist — EXACT R10 verified kernel (44us) ----
__global__ __launch_bounds__(256, 3)
void k_main(const float* __restrict__ gt, const float* __restrict__ anc,
            float* __restrict__ wavemax, uint32_t* __restrict__ aux,
            uint16_t* __restrict__ combo, float* __restrict__ out_matches,
            float* __restrict__ out_inds, float* __restrict__ out_anch,
            uint32_t* __restrict__ hist, int* __restrict__ gtmax_bits) {
  const int bid = blockIdx.x, t = threadIdx.x;
  const int b = bid / PB, blk = bid % PB;

  __shared__ float sx1[NGT], sy1[NGT], sx2p[NGT], sy2p[NGT], sar[NGT];
  __shared__ int   ssz[NGT];
  __shared__ int   smax[NGT];
  if (t < NGT) {
    const float* p = gt + (size_t)(b*NGT + t)*5;
    float x1=p[0], y1=p[1], x2=p[2], y2=p[3];
    float w = x2 - x1 + 1.0f, h = y2 - y1 + 1.0f;
    sx1[t]=x1; sy1[t]=y1; sx2p[t]=x2+1.0f; sy2p[t]=y2+1.0f; sar[t]=w*h;
    ssz[t] = (w==1.0f) && (h==1.0f);
    smax[t] = 0xBF800000;   // bits of -1.0f; all real wavemax >= 0.0f
  }
  __syncthreads();

  const float4* a4 = (const float4*)anc;
  const int base = blk*CHUNK + t;
  const int lane = t & 63;
  float4 av[APT]; float aarea[APT], ax2p[APT], ay2p[APT];
  bool anz[APT], valid[APT];
#pragma unroll
  for (int j=0;j<APT;j++) {
    int n = base + j*256;
    valid[j] = n < NANCH;
    if (n > NANCH-1) n = NANCH-1;   // clamped dup: max-neutral, outputs skipped
    av[j] = a4[n];
    float aw = av[j].z-av[j].x+1.0f, ah = av[j].w-av[j].y+1.0f;
    aarea[j] = aw*ah;
    anz[j] = (aw==1.0f)&&(ah==1.0f);
    ax2p[j] = av[j].z + 1.0f;
    ay2p[j] = av[j].w + 1.0f;
  }
  float best[APT]; int arg[APT]; uint32_t Mloc[APT];
#pragma unroll
  for (int j=0;j<APT;j++) { best[j]=-3.0f; arg[j]=0; Mloc[j]=0u; }
  uint32_t kmask = 0u; float wm = 0.0f;
  // ---- hot loop: rolled over k; DPP wave-max fused per-k ----
  for (int k=0;k<NGT;k++) {
    float kx1=sx1[k], ky1=sy1[k], kx2p=sx2p[k], ky2p=sy2p[k], kar=sar[k];
    bool kz = ssz[k];
    float ovv[APT]; float tmk = -3.0f;
#pragma unroll
    for (int j=0;j<APT;j++) {
      float iw = fminf(ax2p[j], kx2p) - fmaxf(av[j].x, kx1);
      float ih = fminf(ay2p[j], ky2p) - fmaxf(av[j].y, ky1);
      float inter = fmaxf(iw,0.0f)*fmaxf(ih,0.0f);
      float ov = inter * __builtin_amdgcn_rcpf((aarea[j] + kar) - inter);
      if (kz)     ov = 0.0f;
      if (anz[j]) ov = -1.0f;
      ovv[j] = ov;
      if (ov > best[j]) { best[j] = ov; arg[j] = k; }  // first-occurrence argmax
      tmk = fmaxf(tmk, ov);
    }
#pragma unroll
    for (int j=0;j<APT;j++) if (ovv[j] == tmk) Mloc[j] |= (1u<<k);
    const float sv = wave_max64(tmk);
    if (tmk == sv)  kmask |= (1u<<k);
    if (lane == k)  wm = sv;
  }
  // ---- post-loop: store wave max, block/global gt_max reduce ----
  const int wid = bid*4 + (t>>6);
  if (lane < NGT) {
    wavemax[(size_t)wid*NGT + lane] = wm;             // one 80B wave store
    atomicMax(&smax[lane], __float_as_int(wm));       // block-level reduce
  }
  __syncthreads();
  if (t < NGT) atomicMax(&gtmax_bits[b*NGT + t], smax[t]);  // 20 atomics/block
  // ---- outputs + approx hist (code' = flags only; promotions fixed later) ----
  float4* oa4 = (float4*)out_anch;
  const bool owner = (b == (blk & 7));   // spread inds/anch writes over batches
#pragma unroll
  for (int j=0;j<APT;j++) {
    int n = base + j*256;
    if (!valid[j]) continue;
    uint32_t a = ((Mloc[j] & kmask)<<2) |
                 ((best[j] >= 0.7f) ? 2u : 0u) | ((best[j] < 0.3f) ? 1u : 0u);
    aux[(size_t)b*NANCH + n] = a;
    out_matches[(size_t)b*NANCH + n] = (float)(arg[j] + b*NGT);
    if (owner) { out_inds[n] = (float)n; oa4[n] = av[j]; }
    if (a & 3u) {                         // code' != 0: hash + hist + combo
      uint32_t f = (uint32_t)(b*NANCH + n);
      bool isfg = (a & 2u) != 0u;
      uint32_t rb14 = rbits23(isfg?KF0:KG0, isfg?KF1:KG1, f) >> 9;
      combo[(size_t)b*NANCH + n] = (uint16_t)rb14;
      if (isfg)                           // fg: sparse, full-range coarse bins
        atomicAdd(&hist[b*2*HBINS + (rb14>>4)], 1u);
      else if (rb14 < HBINS)              // bg: fine bins, cutoff region only
        atomicAdd(&hist[b*2*HBINS + HBINS + rb14], 1u);
    }
  }
}

// ---- K2: thresholds via PER-WAVE scan (wave0=fg, wave1=bg; 2 barriers
// total — replaces the 256-thread 32-barrier LDS scan), then labels. ----
__global__ __launch_bounds__(256, 4)
void k_final(const uint32_t* __restrict__ aux, const uint16_t* __restrict__ combo,
             const float* __restrict__ wavemax, const int* __restrict__ gtmax_bits,
             const uint32_t* __restrict__ hist, float* __restrict__ out_labels) {
  const int bid = blockIdx.x, t = threadIdx.x;
  const int b = bid / PB, blk = bid % PB;
  const int lane = t & 63;
  const int w = t >> 6;
  const int wid = bid*4 + w;
  __shared__ uint32_t s_thr[2];
  __shared__ uint32_t s_fgtot;

  // ---- wk: does this wave achieve the global gt_max for gt k? ----
  bool cond = false;
  if (lane < NGT) {
    float gv = __int_as_float(gtmax_bits[b*NGT + lane]);
    float rep = (gv == 0.0f) ? 1e-5f : gv;            // ref's gt_max fixup
    cond = (wavemax[(size_t)wid*NGT + lane] == rep);
  }
  uint32_t wk = (uint32_t)__ballot(cond);

  // ---- per-wave threshold scan: lane sums 16 bins; 6-step shfl_up scan ----
  uint4 hv0, hv1, hv2, hv3;
  uint32_t mys = 0, myincl = 0;
  if (w < 2) {
    const uint4* h4 = (const uint4*)(hist + b*2*HBINS + w*HBINS + lane*16);
    hv0 = h4[0]; hv1 = h4[1]; hv2 = h4[2]; hv3 = h4[3];
    mys = hv0.x+hv0.y+hv0.z+hv0.w + hv1.x+hv1.y+hv1.z+hv1.w
        + hv2.x+hv2.y+hv2.z+hv2.w + hv3.x+hv3.y+hv3.z+hv3.w;
    uint32_t x = mys;
#pragma unroll
    for (int d=1; d<64; d<<=1) {
      uint32_t v = __shfl_up(x, d, 64);
      if (lane >= d) x += v;
    }
    myincl = x;                                        // inclusive prefix
    if (w == 0 && lane == 63) s_fgtot = myincl;        // fg total for bg target
  }
  __syncthreads();                                     // barrier 1
  if (w < 2) {
    uint32_t total  = __shfl(myincl, 63, 64);
    uint32_t keptfg = (s_fgtot < 128u) ? s_fgtot : 128u;
    uint32_t target = (w == 0) ? 128u : (256u - keptfg);
    if (total <= target) {
      if (lane == 0) s_thr[w] = (w == 0) ? (HBINS-1u) : 0x3FFFu;  // keep all
    } else {
      uint32_t excl = myincl - mys;
      if (excl < target && target <= myincl) {         // unique owner lane
        uint32_t bins[16] = { hv0.x,hv0.y,hv0.z,hv0.w, hv1.x,hv1.y,hv1.z,hv1.w,
                              hv2.x,hv2.y,hv2.z,hv2.w, hv3.x,hv3.y,hv3.z,hv3.w };
        uint32_t cum = excl, jj = lane*16;
        bool done = false;
#pragma unroll
        for (int i=0;i<16;i++) {                       // static idx (rule #20)
          if (!done) {
            if (cum + bins[i] >= target) { jj = lane*16 + i; done = true; }
            else cum += bins[i];
          }
        }
        s_thr[w] = jj;          // fg: coarse units; bg: fine units
      }
    }
  }
  __syncthreads();                                     // barrier 2
  const uint32_t rF = s_thr[0], rB = s_thr[1];

  // ---- labels: true code; rb from combo (recompute only for promotions) ----
  const int base = blk*CHUNK + t;
#pragma unroll
  for (int j=0;j<APT;j++) {
    int n = base + j*256; if (n >= NANCH) break;
    uint32_t a = aux[(size_t)b*NANCH + n];
    uint32_t rb14 = combo[(size_t)b*NANCH + n];
    uint32_t code = (a & 1u) ? 1u : 0u;
    if ((a>>2) & wk) code = 2u;                       // keep (achieves gt_max)
    if (a & 2u) code = 2u;                            // best >= 0.7
    float o = -1.0f;
    if (code == 1u) {
      o = (rb14 <= rB) ? 0.0f : -1.0f;                // fine compare
    } else if (code == 2u) {
      if (!(a & 2u))                                  // promoted: fg-key rehash
        rb14 = rbits23(KF0, KF1, (uint32_t)(b*NANCH + n)) >> 9;
      o = ((rb14>>4) <= rF) ? 1.0f : -1.0f;           // coarse compare
    }
    out_labels[(size_t)b*NANCH + n] = o;
  }
}

extern "C" void kernel_launch(void* const* d_in, const int* in_sizes, int n_in,
                              void* d_out, int out_size, void* d_ws, size_t ws_size,
                              hipStream_t stream) {
  const float* gt  = (const float*)d_in[1];   // gt_boxes (8,20,5) f32
  const float* anc = (const float*)d_in[4];   // anchors (1,200000,4) f32

  float* out         = (float*)d_out;
  float* out_labels  = out;                                  // [0, 1.6M)
  float* out_matches = out + (size_t)BATCH*NANCH;            // [1.6M, 3.2M)
  float* out_inds    = out + (size_t)2*BATCH*NANCH;          // [3.2M, 3.4M)
  float* out_anch    = out_inds + NANCH;                     // [3.4M, 4.2M)

  char* ws = (char*)d_ws;
  int*      gtmax   = (int*)(ws + 0);             // 160 words; 0xAA poison is a
                                                  // valid atomicMax identity
  uint32_t* hist    = (uint32_t*)(ws + 1024);     // 64 KB (memset node below)
  float*    wavemax = (float*)(ws + 66560);       // 3072 waves * 20 * 4 = 245,760
  uint32_t* aux     = (uint32_t*)(ws + 312320);   // 6.4 MB
  uint16_t* combo   = (uint16_t*)(ws + 6712320);  // 3.2 MB

  // zero hist before k_main's atomics (graph-capture-safe stream memset)
  (void)hipMemsetAsync(hist, 0, HWORDS*sizeof(uint32_t), stream);

  k_main <<<GRID, 256, 0, stream>>>(gt, anc, wavemax, aux, combo, out_matches,
                                    out_inds, out_anch, hist, gtmax);
  k_final<<<GRID, 256, 0, stream>>>(aux, combo, wavemax, gtmax, hist, out_labels);
}

// Round 13
// 113.584 us; speedup vs baseline: 1.0615x; 1.0134x over previous
//
#include <hip/hip_runtime.h>
#include <stdint.h>

#pragma clang fp contract(off)

#define BATCH 8
#define NANCH 200000
#define NGT   20
#define APT   9             // R11: APT=3 regressed (+17% total inst); 9 optimal
#define CHUNK (256*APT)     // 2304
#define PB    96            // chunks per batch; 96*2304 = 221184 >= 200000
#define GRID  (PB*BATCH)    // 768 = exactly 3 blocks/CU on 256 CUs
#define HBINS 1024          // fg: coarse bins (rb14>>4); bg: fine bins rb14<1024
#define HWORDS (2*BATCH*HBINS)  // 16384 words = 64 KB total
#define HALF_FLAT 800000u   // (BATCH*NANCH)/2 threefry split

// ---- compile-time threefry for the two split keys ----
constexpr void ctf_round(uint32_t& x0, uint32_t& x1, int r) {
  x0 += x1; x1 = (x1 << r) | (x1 >> (32 - r)); x1 ^= x0;
}
constexpr uint64_t cenc(uint32_t k0, uint32_t k1, uint32_t x0, uint32_t x1) {
  uint32_t k2 = k0 ^ k1 ^ 0x1BD11BDAu;
  x0 += k0; x1 += k1;
  ctf_round(x0,x1,13); ctf_round(x0,x1,15); ctf_round(x0,x1,26); ctf_round(x0,x1,6);
  x0 += k1; x1 += k2 + 1u;
  ctf_round(x0,x1,17); ctf_round(x0,x1,29); ctf_round(x0,x1,16); ctf_round(x0,x1,24);
  x0 += k2; x1 += k0 + 2u;
  ctf_round(x0,x1,13); ctf_round(x0,x1,15); ctf_round(x0,x1,26); ctf_round(x0,x1,6);
  x0 += k0; x1 += k1 + 3u;
  ctf_round(x0,x1,17); ctf_round(x0,x1,29); ctf_round(x0,x1,16); ctf_round(x0,x1,24);
  x0 += k1; x1 += k2 + 4u;
  ctf_round(x0,x1,13); ctf_round(x0,x1,15); ctf_round(x0,x1,26); ctf_round(x0,x1,6);
  x0 += k2; x1 += k0 + 5u;
  return ((uint64_t)x1 << 32) | x0;
}
constexpr uint64_t EA = cenc(0u,42u,0u,2u);
constexpr uint64_t EB = cenc(0u,42u,1u,3u);
#define KF0 ((uint32_t)(EA & 0xFFFFFFFFu))
#define KF1 ((uint32_t)(EB & 0xFFFFFFFFu))
#define KG0 ((uint32_t)(EA >> 32))
#define KG1 ((uint32_t)(EB >> 32))

// ---- runtime threefry ----
__device__ __forceinline__ void tf_round(uint32_t& x0, uint32_t& x1, int r) {
  x0 += x1; x1 = (x1 << r) | (x1 >> (32 - r)); x1 ^= x0;
}
__device__ __forceinline__ void threefry2x32(uint32_t k0, uint32_t k1,
                                             uint32_t x0, uint32_t x1,
                                             uint32_t& o0, uint32_t& o1) {
  uint32_t k2 = k0 ^ k1 ^ 0x1BD11BDAu;
  x0 += k0; x1 += k1;
  tf_round(x0,x1,13); tf_round(x0,x1,15); tf_round(x0,x1,26); tf_round(x0,x1,6);
  x0 += k1; x1 += k2 + 1u;
  tf_round(x0,x1,17); tf_round(x0,x1,29); tf_round(x0,x1,16); tf_round(x0,x1,24);
  x0 += k2; x1 += k0 + 2u;
  tf_round(x0,x1,13); tf_round(x0,x1,15); tf_round(x0,x1,26); tf_round(x0,x1,6);
  x0 += k0; x1 += k1 + 3u;
  tf_round(x0,x1,17); tf_round(x0,x1,29); tf_round(x0,x1,16); tf_round(x0,x1,24);
  x0 += k1; x1 += k2 + 4u;
  tf_round(x0,x1,13); tf_round(x0,x1,15); tf_round(x0,x1,26); tf_round(x0,x1,6);
  x0 += k2; x1 += k0 + 5u;
  o0 = x0; o1 = x1;
}
__device__ __forceinline__ uint32_t rbits23(uint32_t kk0, uint32_t kk1, uint32_t f) {
  uint32_t o0, o1;
  if (f < HALF_FLAT) { threefry2x32(kk0, kk1, f, f + HALF_FLAT, o0, o1); return o0 >> 9; }
  else               { threefry2x32(kk0, kk1, f - HALF_FLAT, f, o0, o1); return o1 >> 9; }
}

// ---- DPP wave64 max-reduce (6 VALU-rate ops, no DS) ----
template<int CTRL>
__device__ __forceinline__ float dppmax(float x) {
  int xi = __float_as_int(x);
  int yi = __builtin_amdgcn_update_dpp(xi, xi, CTRL, 0xf, 0xf, false);
  return fmaxf(x, __int_as_float(yi));
}
__device__ __forceinline__ float wave_max64(float x) {
  x = dppmax<0x0B1>(x);  // quad_perm [1,0,3,2]
  x = dppmax<0x04E>(x);  // quad_perm [2,3,0,1]
  x = dppmax<0x141>(x);  // row_half_mirror
  x = dppmax<0x140>(x);  // row_mirror
  x = dppmax<0x142>(x);  // row_bcast15
  x = dppmax<0x143>(x);  // row_bcast31
  return __int_as_float(__builtin_amdgcn_readlane(__float_as_int(x), 63));
}

// ---- K1: IoU pass + approx hist. R12-verified logic with instruction diet:
//  * anz cndmask -> aarea=+INF at init (ov becomes exactly +0: same flags,
//    same argmax-ties, keep-chain can't fire since rep>=1e-5)
//  * kz cndmask -> wave-uniform branch (exact ref semantics in branch body)
//  * kmask dropped: Mloc bit k = (ovv==sv) directly (ovv<=tmk<=sv => equiv)
//  * av[]/valid[]/anz[] arrays eliminated (out_anch rebuilt from ax2p-1) ----
__global__ __launch_bounds__(256, 3)
void k_main(const float* __restrict__ gt, const float* __restrict__ anc,
            float* __restrict__ wavemax, uint32_t* __restrict__ aux,
            uint16_t* __restrict__ combo, float* __restrict__ out_matches,
            float* __restrict__ out_inds, float* __restrict__ out_anch,
            uint32_t* __restrict__ hist, int* __restrict__ gtmax_bits) {
  const int bid = blockIdx.x, t = threadIdx.x;
  const int b = bid / PB, blk = bid % PB;

  __shared__ float sx1[NGT], sy1[NGT], sx2p[NGT], sy2p[NGT], sar[NGT];
  __shared__ int   ssz[NGT];
  __shared__ int   smax[NGT];
  if (t < NGT) {
    const float* p = gt + (size_t)(b*NGT + t)*5;
    float x1=p[0], y1=p[1], x2=p[2], y2=p[3];
    float w = x2 - x1 + 1.0f, h = y2 - y1 + 1.0f;
    sx1[t]=x1; sy1[t]=y1; sx2p[t]=x2+1.0f; sy2p[t]=y2+1.0f; sar[t]=w*h;
    ssz[t] = (w==1.0f) && (h==1.0f);
    smax[t] = 0xBF800000;   // bits of -1.0f; all real wavemax >= 0.0f
  }
  __syncthreads();

  const float4* a4 = (const float4*)anc;
  const int base = blk*CHUNK + t;
  const int lane = t & 63;
  float ax[APT], ay[APT], aarea[APT], ax2p[APT], ay2p[APT];
#pragma unroll
  for (int j=0;j<APT;j++) {
    int n = base + j*256;
    if (n > NANCH-1) n = NANCH-1;   // clamped dup: max-neutral, outputs skipped
    float4 v = a4[n];
    ax[j] = v.x; ay[j] = v.y;
    float aw = v.z-v.x+1.0f, ah = v.w-v.y+1.0f;
    bool anz = (aw==1.0f)&&(ah==1.0f);
    aarea[j] = anz ? __builtin_inff() : aw*ah;   // INF => ov == +0 exactly
    ax2p[j] = v.z + 1.0f;
    ay2p[j] = v.w + 1.0f;
  }
  float best[APT]; int arg[APT]; uint32_t Mloc[APT];
#pragma unroll
  for (int j=0;j<APT;j++) { best[j]=-3.0f; arg[j]=0; Mloc[j]=0u; }
  float wm = 0.0f;
  // ---- hot loop: rolled over k; DPP wave-max fused per-k ----
  for (int k=0;k<NGT;k++) {
    float ovv[APT]; float tmk;
    if (__builtin_expect(ssz[k], 0)) {
      // zero-area gt: ref sets ov=0 for the whole column (exact)
#pragma unroll
      for (int j=0;j<APT;j++) {
        ovv[j] = 0.0f;
        if (0.0f > best[j]) { best[j] = 0.0f; arg[j] = k; }
      }
      tmk = 0.0f;
    } else {
      float kx1=sx1[k], ky1=sy1[k], kx2p=sx2p[k], ky2p=sy2p[k], kar=sar[k];
      tmk = -3.0f;
#pragma unroll
      for (int j=0;j<APT;j++) {
        float iw = fminf(ax2p[j], kx2p) - fmaxf(ax[j], kx1);
        float ih = fminf(ay2p[j], ky2p) - fmaxf(ay[j], ky1);
        float inter = fmaxf(iw,0.0f)*fmaxf(ih,0.0f);
        float ov = inter * __builtin_amdgcn_rcpf((aarea[j] + kar) - inter);
        ovv[j] = ov;
        if (ov > best[j]) { best[j] = ov; arg[j] = k; }  // first-occurrence argmax
        tmk = fmaxf(tmk, ov);
      }
    }
    const float sv = wave_max64(tmk);
#pragma unroll
    for (int j=0;j<APT;j++) if (ovv[j] == sv) Mloc[j] |= (1u<<k);
    if (lane == k)  wm = sv;
  }
  // ---- post-loop: store wave max, block/global gt_max reduce ----
  const int wid = bid*4 + (t>>6);
  if (lane < NGT) {
    wavemax[(size_t)wid*NGT + lane] = wm;             // one 80B wave store
    atomicMax(&smax[lane], __float_as_int(wm));       // block-level reduce
  }
  __syncthreads();
  if (t < NGT) atomicMax(&gtmax_bits[b*NGT + t], smax[t]);  // 20 atomics/block
  // ---- outputs + approx hist (code' = flags only; promotions fixed later) ----
  float4* oa4 = (float4*)out_anch;
  const bool owner = (b == (blk & 7));   // spread inds/anch writes over batches
#pragma unroll
  for (int j=0;j<APT;j++) {
    int n = base + j*256;
    if (n >= NANCH) continue;
    uint32_t a = (Mloc[j]<<2) |
                 ((best[j] >= 0.7f) ? 2u : 0u) | ((best[j] < 0.3f) ? 1u : 0u);
    aux[(size_t)b*NANCH + n] = a;
    out_matches[(size_t)b*NANCH + n] = (float)(arg[j] + b*NGT);
    if (owner) {
      out_inds[n] = (float)n;
      oa4[n] = make_float4(ax[j], ay[j], ax2p[j]-1.0f, ay2p[j]-1.0f);
    }
    if (a & 3u) {                         // code' != 0: hash + hist + combo
      uint32_t f = (uint32_t)(b*NANCH + n);
      bool isfg = (a & 2u) != 0u;
      uint32_t rb14 = rbits23(isfg?KF0:KG0, isfg?KF1:KG1, f) >> 9;
      combo[(size_t)b*NANCH + n] = (uint16_t)rb14;
      if (isfg)                           // fg: sparse, full-range coarse bins
        atomicAdd(&hist[b*2*HBINS + (rb14>>4)], 1u);
      else if (rb14 < HBINS)              // bg: fine bins, cutoff region only
        atomicAdd(&hist[b*2*HBINS + HBINS + rb14], 1u);
    }
  }
}

// ---- K2: thresholds via per-wave scan (R12 verified), then labels ----
__global__ __launch_bounds__(256, 4)
void k_final(const uint32_t* __restrict__ aux, const uint16_t* __restrict__ combo,
             const float* __restrict__ wavemax, const int* __restrict__ gtmax_bits,
             const uint32_t* __restrict__ hist, float* __restrict__ out_labels) {
  const int bid = blockIdx.x, t = threadIdx.x;
  const int b = bid / PB, blk = bid % PB;
  const int lane = t & 63;
  const int w = t >> 6;
  const int wid = bid*4 + w;
  __shared__ uint32_t s_thr[2];
  __shared__ uint32_t s_fgtot;

  // ---- wk: does this wave achieve the global gt_max for gt k? ----
  bool cond = false;
  if (lane < NGT) {
    float gv = __int_as_float(gtmax_bits[b*NGT + lane]);
    float rep = (gv == 0.0f) ? 1e-5f : gv;            // ref's gt_max fixup
    cond = (wavemax[(size_t)wid*NGT + lane] == rep);
  }
  uint32_t wk = (uint32_t)__ballot(cond);

  // ---- per-wave threshold scan: lane sums 16 bins; 6-step shfl_up scan ----
  uint4 hv0, hv1, hv2, hv3;
  uint32_t mys = 0, myincl = 0;
  if (w < 2) {
    const uint4* h4 = (const uint4*)(hist + b*2*HBINS + w*HBINS + lane*16);
    hv0 = h4[0]; hv1 = h4[1]; hv2 = h4[2]; hv3 = h4[3];
    mys = hv0.x+hv0.y+hv0.z+hv0.w + hv1.x+hv1.y+hv1.z+hv1.w
        + hv2.x+hv2.y+hv2.z+hv2.w + hv3.x+hv3.y+hv3.z+hv3.w;
    uint32_t x = mys;
#pragma unroll
    for (int d=1; d<64; d<<=1) {
      uint32_t v = __shfl_up(x, d, 64);
      if (lane >= d) x += v;
    }
    myincl = x;                                        // inclusive prefix
    if (w == 0 && lane == 63) s_fgtot = myincl;        // fg total for bg target
  }
  __syncthreads();                                     // barrier 1
  if (w < 2) {
    uint32_t total  = __shfl(myincl, 63, 64);
    uint32_t keptfg = (s_fgtot < 128u) ? s_fgtot : 128u;
    uint32_t target = (w == 0) ? 128u : (256u - keptfg);
    if (total <= target) {
      if (lane == 0) s_thr[w] = (w == 0) ? (HBINS-1u) : 0x3FFFu;  // keep all
    } else {
      uint32_t excl = myincl - mys;
      if (excl < target && target <= myincl) {         // unique owner lane
        uint32_t bins[16] = { hv0.x,hv0.y,hv0.z,hv0.w, hv1.x,hv1.y,hv1.z,hv1.w,
                              hv2.x,hv2.y,hv2.z,hv2.w, hv3.x,hv3.y,hv3.z,hv3.w };
        uint32_t cum = excl, jj = lane*16;
        bool done = false;
#pragma unroll
        for (int i=0;i<16;i++) {                       // static idx (rule #20)
          if (!done) {
            if (cum + bins[i] >= target) { jj = lane*16 + i; done = true; }
            else cum += bins[i];
          }
        }
        s_thr[w] = jj;          // fg: coarse units; bg: fine units
      }
    }
  }
  __syncthreads();                                     // barrier 2
  const uint32_t rF = s_thr[0], rB = s_thr[1];

  // ---- labels: true code; rb from combo (recompute only for promotions) ----
  const int base = blk*CHUNK + t;
#pragma unroll
  for (int j=0;j<APT;j++) {
    int n = base + j*256; if (n >= NANCH) break;
    uint32_t a = aux[(size_t)b*NANCH + n];
    uint32_t rb14 = combo[(size_t)b*NANCH + n];
    uint32_t code = (a & 1u) ? 1u : 0u;
    if ((a>>2) & wk) code = 2u;                       // keep (achieves gt_max)
    if (a & 2u) code = 2u;                            // best >= 0.7
    float o = -1.0f;
    if (code == 1u) {
      o = (rb14 <= rB) ? 0.0f : -1.0f;                // fine compare
    } else if (code == 2u) {
      if (!(a & 2u))                                  // promoted: fg-key rehash
        rb14 = rbits23(KF0, KF1, (uint32_t)(b*NANCH + n)) >> 9;
      o = ((rb14>>4) <= rF) ? 1.0f : -1.0f;           // coarse compare
    }
    out_labels[(size_t)b*NANCH + n] = o;
  }
}

extern "C" void kernel_launch(void* const* d_in, const int* in_sizes, int n_in,
                              void* d_out, int out_size, void* d_ws, size_t ws_size,
                              hipStream_t stream) {
  const float* gt  = (const float*)d_in[1];   // gt_boxes (8,20,5) f32
  const float* anc = (const float*)d_in[4];   // anchors (1,200000,4) f32

  float* out         = (float*)d_out;
  float* out_labels  = out;                                  // [0, 1.6M)
  float* out_matches = out + (size_t)BATCH*NANCH;            // [1.6M, 3.2M)
  float* out_inds    = out + (size_t)2*BATCH*NANCH;          // [3.2M, 3.4M)
  float* out_anch    = out_inds + NANCH;                     // [3.4M, 4.2M)

  char* ws = (char*)d_ws;
  int*      gtmax   = (int*)(ws + 0);             // 160 words; 0xAA poison is a
                                                  // valid atomicMax identity
  uint32_t* hist    = (uint32_t*)(ws + 1024);     // 64 KB (memset node below)
  float*    wavemax = (float*)(ws + 66560);       // 3072 waves * 20 * 4 = 245,760
  uint32_t* aux     = (uint32_t*)(ws + 312320);   // 6.4 MB
  uint16_t* combo   = (uint16_t*)(ws + 6712320);  // 3.2 MB

  // zero hist before k_main's atomics (graph-capture-safe stream memset)
  (void)hipMemsetAsync(hist, 0, HWORDS*sizeof(uint32_t), stream);

  k_main <<<GRID, 256, 0, stream>>>(gt, anc, wavemax, aux, combo, out_matches,
                                    out_inds, out_anch, hist, gtmax);
  k_final<<<GRID, 256, 0, stream>>>(aux, combo, wavemax, gtmax, hist, out_labels);
}